// Round 1
// baseline (438.680 us; speedup 1.0000x reference)
//
#include <hip/hip_runtime.h>
#include <cstdio>
#include <cstdint>

#define INP 32
#define OUTD 32
#define NREL 16
#define NBASE 8

// ---------------------------------------------------------------------------
// k_prep: rel_w[r][i][o] = sum_b w_comp[r][b] * weight[b][i][o]   (16x32x32)
//         relA[r][o]     = A_b[o] + sum_i attn_emb[r][i] * A_w[64+i][o]
// grid 64 x 256 = 16384 threads, one rel_w element each.
// ---------------------------------------------------------------------------
__global__ void k_prep(const float* __restrict__ weight, const float* __restrict__ w_comp,
                       const float* __restrict__ attn_emb, const float* __restrict__ A_w,
                       const float* __restrict__ A_b,
                       float* __restrict__ rel_w, float* __restrict__ relA) {
    int idx = blockIdx.x * 256 + threadIdx.x;          // 0..16383
    int r = idx >> 10, io = idx & 1023;
    float acc = 0.f;
    #pragma unroll
    for (int b = 0; b < NBASE; ++b)
        acc += w_comp[r * NBASE + b] * weight[b * 1024 + io];
    rel_w[idx] = acc;
    if (idx < NREL * 32) {
        int rr = idx >> 5, o = idx & 31;
        float a = A_b[o];
        #pragma unroll 8
        for (int i = 0; i < 32; ++i)
            a += attn_emb[rr * 32 + i] * A_w[(64 + i) * 32 + o];
        relA[idx] = a;
    }
}

// ---------------------------------------------------------------------------
// k_degree: in_deg[dst[e]] += 1
// ---------------------------------------------------------------------------
__global__ void k_degree(const int* __restrict__ dst, float* __restrict__ in_deg, int E) {
    int e = blockIdx.x * 256 + threadIdx.x;
    if (e < E) atomicAdd(&in_deg[dst[e]], 1.0f);
}

// ---------------------------------------------------------------------------
// k_scale_sum: scale_sum += sum_n log(in_deg[n]+1), one atomic per block
// ---------------------------------------------------------------------------
__global__ void k_scale_sum(const float* __restrict__ in_deg, float* __restrict__ scale_sum, int N) {
    __shared__ float sd[256];
    int t = threadIdx.x;
    int n = blockIdx.x * 256 + t;
    sd[t] = (n < N) ? logf(in_deg[n] + 1.0f) : 0.f;
    __syncthreads();
    #pragma unroll
    for (int s = 128; s > 0; s >>= 1) {
        if (t < s) sd[t] += sd[t + s];
        __syncthreads();
    }
    if (t == 0) atomicAdd(scale_sum, sd[0]);
}

// ---------------------------------------------------------------------------
// k_node_pre: per-node precompute of hA1 = h@A_w[0:32], hA2 = h@A_w[32:64],
//             curr = h@self_loop_weight.  8 nodes/block, W staged in LDS.
// ---------------------------------------------------------------------------
__global__ __launch_bounds__(256) void k_node_pre(const float* __restrict__ h,
        const float* __restrict__ A_w, const float* __restrict__ slw,
        float* __restrict__ hA1, float* __restrict__ hA2, float* __restrict__ curr, int N) {
    __shared__ __align__(16) float Wall[32 * 128];   // [i][c]: c<32 A1, <64 A2, <96 slw, pad
    __shared__ float hbuf[8 * 33];
    int t = threadIdx.x;
    #pragma unroll
    for (int k = 0; k < 16; ++k) {
        int idx = t + 256 * k;                       // 0..4095
        int i = idx >> 7, c = idx & 127;
        float v = 0.f;
        if (c < 32)       v = A_w[i * 32 + c];
        else if (c < 64)  v = A_w[(32 + i) * 32 + (c - 32)];
        else if (c < 96)  v = slw[i * 32 + (c - 64)];
        Wall[idx] = v;
    }
    int n0 = blockIdx.x * 8;
    {
        int row = t >> 5, col = t & 31;
        int n = n0 + row;
        hbuf[row * 33 + col] = (n < N) ? h[n * 32 + col] : 0.f;
    }
    __syncthreads();
    int nl = t >> 5;               // 0..7
    int c4 = (t & 31) * 4;         // 0..124
    float4 acc = {0.f, 0.f, 0.f, 0.f};
    #pragma unroll 8
    for (int i = 0; i < 32; ++i) {
        float hv = hbuf[nl * 33 + i];
        float4 w = *(const float4*)&Wall[i * 128 + c4];
        acc.x += hv * w.x; acc.y += hv * w.y; acc.z += hv * w.z; acc.w += hv * w.w;
    }
    int n = n0 + nl;
    if (n < N && c4 < 96) {
        float* p = (c4 < 32) ? &hA1[n * 32 + c4]
                 : (c4 < 64) ? &hA2[n * 32 + (c4 - 32)]
                             : &curr[n * 32 + (c4 - 64)];
        *(float4*)p = acc;
    }
}

// ---------------------------------------------------------------------------
// k_hrel: hrel[n][r*32+o] = sum_i h[n][i] * rel_w[r][i][o].
// Dense GEMM [N,32] @ [32,512]. 32 nodes/block, 8 nodes/wave held in regs;
// rel_w read from global as float4 (64KB table, L1/L2-resident), reused 8x.
// ---------------------------------------------------------------------------
__global__ __launch_bounds__(256) void k_hrel(const float* __restrict__ h,
        const float* __restrict__ rel_w, float* __restrict__ hrel, int N) {
    __shared__ float hbuf[32 * 33];
    int t = threadIdx.x;
    int n0 = blockIdx.x * 32;
    #pragma unroll
    for (int k = 0; k < 4; ++k) {
        int idx = t + 256 * k;                        // 0..1023
        int row = idx >> 5, col = idx & 31;
        int n = n0 + row;
        hbuf[row * 33 + col] = (n < N) ? h[n * 32 + col] : 0.f;
    }
    __syncthreads();
    int w = t >> 6;                // wave 0..3 -> nodes 8w..8w+7
    int lane = t & 63;
    const float4* Wg = (const float4*)rel_w;
    // lane covers ro = lane*4 (r=lane>>3) and ro+256 (r=8+lane>>3)
    int base_f4 = (lane >> 3) * 256 + (lane & 7);
    float4 a0[8], a1[8];
    #pragma unroll
    for (int j = 0; j < 8; ++j) {
        a0[j] = make_float4(0.f, 0.f, 0.f, 0.f);
        a1[j] = make_float4(0.f, 0.f, 0.f, 0.f);
    }
    int brow = w * 8;
    #pragma unroll 4
    for (int i = 0; i < 32; ++i) {
        float4 w0 = Wg[base_f4 + i * 8];
        float4 w1 = Wg[base_f4 + i * 8 + 2048];
        #pragma unroll
        for (int j = 0; j < 8; ++j) {
            float hv = hbuf[(brow + j) * 33 + i];
            a0[j].x += hv * w0.x; a0[j].y += hv * w0.y; a0[j].z += hv * w0.z; a0[j].w += hv * w0.w;
            a1[j].x += hv * w1.x; a1[j].y += hv * w1.y; a1[j].z += hv * w1.z; a1[j].w += hv * w1.w;
        }
    }
    #pragma unroll
    for (int j = 0; j < 8; ++j) {
        int n = n0 + brow + j;
        if (n < N) {
            *(float4*)&hrel[(size_t)n * 512 + lane * 4]       = a0[j];
            *(float4*)&hrel[(size_t)n * 512 + 256 + lane * 4] = a1[j];
        }
    }
}

// ---------------------------------------------------------------------------
// k_edge: per-edge attention + gather msg from hrel + atomic scatter.
// 32 lanes per edge, 8 edges per block.
// ---------------------------------------------------------------------------
__global__ __launch_bounds__(256) void k_edge(const float* __restrict__ hrel,
        const float* __restrict__ hA1, const float* __restrict__ hA2,
        const float* __restrict__ relA, const float* __restrict__ B_w,
        const float* __restrict__ B_b,
        const int* __restrict__ src, const int* __restrict__ dst, const int* __restrict__ et,
        float* __restrict__ agg, int E) {
    int t = threadIdx.x;
    int e = blockIdx.x * 8 + (t >> 5);
    int o = t & 31;
    if (e >= E) return;
    int s = src[e], d = dst[e], r = et[e];
    float msg = hrel[(size_t)s * 512 + r * 32 + o];
    float z = hA1[s * 32 + o] + hA2[d * 32 + o] + relA[r * 32 + o];
    float p = fmaxf(z, 0.f) * B_w[o];
    #pragma unroll
    for (int off = 16; off > 0; off >>= 1) p += __shfl_xor(p, off, 32);
    float a = 1.0f / (1.0f + __expf(-(p + B_b[0])));
    atomicAdd(&agg[(size_t)d * 32 + o], a * msg);
}

// ---------------------------------------------------------------------------
// k_edge_slow: fallback when ws can't hold hrel — msg computed from global
// rel_w (L1/L2-cached 64KB table). Correctness net, not speed.
// ---------------------------------------------------------------------------
__global__ __launch_bounds__(256) void k_edge_slow(const float* __restrict__ h,
        const float* __restrict__ rel_w,
        const float* __restrict__ hA1, const float* __restrict__ hA2,
        const float* __restrict__ relA, const float* __restrict__ B_w,
        const float* __restrict__ B_b,
        const int* __restrict__ src, const int* __restrict__ dst, const int* __restrict__ et,
        float* __restrict__ agg, int E) {
    __shared__ float hbuf[8 * 33];
    int t = threadIdx.x;
    int g = t >> 5, o = t & 31;
    int e = blockIdx.x * 8 + g;
    bool active = (e < E);
    int s = 0, d = 0, r = 0;
    if (active) { s = src[e]; d = dst[e]; r = et[e]; }
    if (active) hbuf[g * 33 + o] = h[s * 32 + o];
    __syncthreads();
    if (!active) return;
    float acc = 0.f;
    #pragma unroll 8
    for (int i = 0; i < 32; ++i)
        acc += hbuf[g * 33 + i] * rel_w[r * 1024 + i * 32 + o];
    float z = hA1[s * 32 + o] + hA2[d * 32 + o] + relA[r * 32 + o];
    float p = fmaxf(z, 0.f) * B_w[o];
    #pragma unroll
    for (int off = 16; off > 0; off >>= 1) p += __shfl_xor(p, off, 32);
    float a = 1.0f / (1.0f + __expf(-(p + B_b[0])));
    atomicAdd(&agg[(size_t)d * 32 + o], a * acc);
}

// ---------------------------------------------------------------------------
// k_out: out = relu(curr + (scale/scale_mean) * agg / max(deg,1) + bias)
// ---------------------------------------------------------------------------
__global__ void k_out(const float* __restrict__ curr, const float* __restrict__ agg,
        const float* __restrict__ in_deg, const float* __restrict__ scale_sum,
        const float* __restrict__ bias, float* __restrict__ out, int N) {
    int gid = blockIdx.x * 256 + threadIdx.x;
    if (gid >= N * 32) return;
    int n = gid >> 5, o = gid & 31;
    float deg = in_deg[n];
    float scale = logf(deg + 1.0f);
    float smean = scale_sum[0] / (float)N;
    float v = curr[gid] + (scale / smean) * agg[gid] / fmaxf(deg, 1.0f) + bias[o];
    out[gid] = fmaxf(v, 0.f);
}

extern "C" void kernel_launch(void* const* d_in, const int* in_sizes, int n_in,
                              void* d_out, int out_size, void* d_ws, size_t ws_size,
                              hipStream_t stream) {
    const float* h        = (const float*)d_in[0];
    const float* weight   = (const float*)d_in[1];
    const float* w_comp   = (const float*)d_in[2];
    const float* slw      = (const float*)d_in[3];
    const float* bias     = (const float*)d_in[4];
    const float* attn_emb = (const float*)d_in[5];
    const float* A_w      = (const float*)d_in[6];
    const float* A_b      = (const float*)d_in[7];
    const float* B_w      = (const float*)d_in[8];
    const float* B_b      = (const float*)d_in[9];
    const int*   src      = (const int*)d_in[10];
    const int*   dst      = (const int*)d_in[11];
    const int*   et       = (const int*)d_in[12];
    float*       out      = (float*)d_out;

    int N = in_sizes[0] / INP;
    int E = in_sizes[10];

    float* ws = (float*)d_ws;
    size_t off = 0;
    auto alloc = [&](size_t nfloat) {
        float* p = ws + off;
        off += (nfloat + 15) & ~((size_t)15);   // keep 16-float (64B) alignment
        return p;
    };
    float* agg     = alloc((size_t)N * 32);
    float* in_deg  = alloc((size_t)N);
    float* scale_s = alloc(1);
    size_t zero_floats = off;                    // agg + in_deg + scale contiguous at base
    float* rel_w   = alloc((size_t)NREL * 1024);
    float* relA    = alloc((size_t)NREL * 32);
    float* hA1     = alloc((size_t)N * 32);
    float* hA2     = alloc((size_t)N * 32);
    float* curr    = alloc((size_t)N * 32);
    size_t baseNeed = off * sizeof(float);
    float* hrel    = alloc((size_t)N * 512);
    size_t fullNeed = off * sizeof(float);

    if (ws_size < baseNeed) {
        fprintf(stderr, "kernel_launch: ws too small (%zu < %zu bytes) — no work launched\n",
                ws_size, baseNeed);
        return;
    }
    bool full = (ws_size >= fullNeed);

    hipMemsetAsync(d_ws, 0, zero_floats * sizeof(float), stream);

    k_prep<<<64, 256, 0, stream>>>(weight, w_comp, attn_emb, A_w, A_b, rel_w, relA);
    k_degree<<<(E + 255) / 256, 256, 0, stream>>>(dst, in_deg, E);
    k_scale_sum<<<(N + 255) / 256, 256, 0, stream>>>(in_deg, scale_s, N);
    k_node_pre<<<(N + 7) / 8, 256, 0, stream>>>(h, A_w, slw, hA1, hA2, curr, N);

    if (full) {
        k_hrel<<<(N + 31) / 32, 256, 0, stream>>>(h, rel_w, hrel, N);
        k_edge<<<(E + 7) / 8, 256, 0, stream>>>(hrel, hA1, hA2, relA, B_w, B_b,
                                                src, dst, et, agg, E);
    } else {
        k_edge_slow<<<(E + 7) / 8, 256, 0, stream>>>(h, rel_w, hA1, hA2, relA, B_w, B_b,
                                                     src, dst, et, agg, E);
    }

    k_out<<<((size_t)N * 32 + 255) / 256, 256, 0, stream>>>(curr, agg, in_deg, scale_s,
                                                            bias, out, N);
}

// Round 3
// 399.725 us; speedup vs baseline: 1.0975x; 1.0975x over previous
//
#include <hip/hip_runtime.h>
#include <cstdio>
#include <cstdint>

#define INP 32
#define NREL 16
#define NBASE 8

// ---------------------------------------------------------------------------
// DPP-based partial-row add (VALU pipe, not LDS): x += dpp_shifted(x).
// CTRL must be a compile-time constant -> template parameter.
// ---------------------------------------------------------------------------
template <int CTRL>
__device__ __forceinline__ float dpp_add_f(float x) {
    int xi = __builtin_bit_cast(int, x);
    int yi = __builtin_amdgcn_update_dpp(0, xi, CTRL, 0xF, 0xF, true);
    return x + __builtin_bit_cast(float, yi);
}

// ---------------------------------------------------------------------------
// k_prep: rel_w[r][i][o] = sum_b w_comp[r][b] * weight[b][i][o]   (16x32x32)
//         relA[r][o]     = A_b[o] + sum_i attn_emb[r][i] * A_w[64+i][o]
// ---------------------------------------------------------------------------
__global__ void k_prep(const float* __restrict__ weight, const float* __restrict__ w_comp,
                       const float* __restrict__ attn_emb, const float* __restrict__ A_w,
                       const float* __restrict__ A_b,
                       float* __restrict__ rel_w, float* __restrict__ relA) {
    int idx = blockIdx.x * 256 + threadIdx.x;          // 0..16383
    int r = idx >> 10, io = idx & 1023;
    float acc = 0.f;
    #pragma unroll
    for (int b = 0; b < NBASE; ++b)
        acc += w_comp[r * NBASE + b] * weight[b * 1024 + io];
    rel_w[idx] = acc;
    if (idx < NREL * 32) {
        int rr = idx >> 5, o = idx & 31;
        float a = A_b[o];
        #pragma unroll 8
        for (int i = 0; i < 32; ++i)
            a += attn_emb[rr * 32 + i] * A_w[(64 + i) * 32 + o];
        relA[idx] = a;
    }
}

// ---------------------------------------------------------------------------
// k_hist: deg[dst[e]] += 1  (int atomics, avg 16 hits per address)
// ---------------------------------------------------------------------------
__global__ void k_hist(const int* __restrict__ dst, int* __restrict__ deg, int E) {
    int e = blockIdx.x * 256 + threadIdx.x;
    if (e < E) atomicAdd(&deg[dst[e]], 1);
}

// ---------------------------------------------------------------------------
// k_scan1: per-block exclusive scan of deg -> rowptr partials + block sums.
// Also accumulates sum of log(deg+1) into scale_s (one atomic per block).
// ---------------------------------------------------------------------------
__global__ __launch_bounds__(256) void k_scan1(const int* __restrict__ deg,
        int* __restrict__ rowptr, int* __restrict__ bsum,
        float* __restrict__ scale_s, int N) {
    __shared__ int sd[256];
    __shared__ float sf[256];
    int t = threadIdx.x;
    int gid = blockIdx.x * 256 + t;
    int v = (gid < N) ? deg[gid] : 0;
    sd[t] = v;
    sf[t] = (gid < N) ? logf((float)v + 1.0f) : 0.f;
    __syncthreads();
    for (int off = 1; off < 256; off <<= 1) {
        int x = (t >= off) ? sd[t - off] : 0;
        __syncthreads();
        sd[t] += x;
        __syncthreads();
    }
    if (gid < N) rowptr[gid] = sd[t] - v;
    if (t == 255) bsum[blockIdx.x] = sd[255];
    for (int s2 = 128; s2 > 0; s2 >>= 1) {
        if (t < s2) sf[t] += sf[t + s2];
        __syncthreads();
    }
    if (t == 0) atomicAdd(scale_s, sf[0]);
}

// ---------------------------------------------------------------------------
// k_scan2: single block scans block sums (in place, exclusive), chunked so any
// nblk works. Writes rowptr[N] = E.
// ---------------------------------------------------------------------------
__global__ __launch_bounds__(1024) void k_scan2(int* __restrict__ bsum,
        int* __restrict__ rowptr, int nblk, int N) {
    __shared__ int sd[1024];
    __shared__ int carry;
    int t = threadIdx.x;
    if (t == 0) carry = 0;
    __syncthreads();
    for (int base = 0; base < nblk; base += 1024) {
        int v = (base + t < nblk) ? bsum[base + t] : 0;
        sd[t] = v;
        __syncthreads();
        for (int off = 1; off < 1024; off <<= 1) {
            int x = (t >= off) ? sd[t - off] : 0;
            __syncthreads();
            sd[t] += x;
            __syncthreads();
        }
        int c = carry;
        if (base + t < nblk) bsum[base + t] = sd[t] - v + c;
        int tot = sd[1023];
        __syncthreads();
        if (t == 0) carry = c + tot;
        __syncthreads();
    }
    if (t == 0) rowptr[N] = carry;
}

// ---------------------------------------------------------------------------
// k_scan3: add block offsets back -> rowptr complete
// ---------------------------------------------------------------------------
__global__ void k_scan3(int* __restrict__ rowptr, const int* __restrict__ bsum, int N) {
    int gid = blockIdx.x * 256 + threadIdx.x;
    if (gid < N) rowptr[gid] += bsum[blockIdx.x];
}

// ---------------------------------------------------------------------------
// k_scatter: dst-sorted edge list; packed = src | (et<<20) (src<2^17, et<16)
// ---------------------------------------------------------------------------
__global__ void k_scatter(const int* __restrict__ src, const int* __restrict__ dst,
        const int* __restrict__ et, const int* __restrict__ rowptr,
        int* __restrict__ cursor, int* __restrict__ packed, int E) {
    int e = blockIdx.x * 256 + threadIdx.x;
    if (e >= E) return;
    int d = dst[e];
    int pos = rowptr[d] + atomicAdd(&cursor[d], 1);
    packed[pos] = src[e] | (et[e] << 20);
}

// ---------------------------------------------------------------------------
// k_node_pre: hA1 = h@A_w[0:32], hA2 = h@A_w[32:64], curr = h@slw
// ---------------------------------------------------------------------------
__global__ __launch_bounds__(256) void k_node_pre(const float* __restrict__ h,
        const float* __restrict__ A_w, const float* __restrict__ slw,
        float* __restrict__ hA1, float* __restrict__ hA2, float* __restrict__ curr, int N) {
    __shared__ __align__(16) float Wall[32 * 128];   // [i][c]: c<32 A1, <64 A2, <96 slw
    __shared__ float hbuf[8 * 33];
    int t = threadIdx.x;
    #pragma unroll
    for (int k = 0; k < 16; ++k) {
        int idx = t + 256 * k;
        int i = idx >> 7, c = idx & 127;
        float v = 0.f;
        if (c < 32)       v = A_w[i * 32 + c];
        else if (c < 64)  v = A_w[(32 + i) * 32 + (c - 32)];
        else if (c < 96)  v = slw[i * 32 + (c - 64)];
        Wall[idx] = v;
    }
    int n0 = blockIdx.x * 8;
    {
        int row = t >> 5, col = t & 31;
        int n = n0 + row;
        hbuf[row * 33 + col] = (n < N) ? h[n * 32 + col] : 0.f;
    }
    __syncthreads();
    int nl = t >> 5;
    int c4 = (t & 31) * 4;
    float4 acc = {0.f, 0.f, 0.f, 0.f};
    #pragma unroll 8
    for (int i = 0; i < 32; ++i) {
        float hv = hbuf[nl * 33 + i];
        float4 w = *(const float4*)&Wall[i * 128 + c4];
        acc.x += hv * w.x; acc.y += hv * w.y; acc.z += hv * w.z; acc.w += hv * w.w;
    }
    int n = n0 + nl;
    if (n < N && c4 < 96) {
        float* p = (c4 < 32) ? &hA1[n * 32 + c4]
                 : (c4 < 64) ? &hA2[n * 32 + (c4 - 32)]
                             : &curr[n * 32 + (c4 - 64)];
        *(float4*)p = acc;
    }
}

// ---------------------------------------------------------------------------
// k_hrel: hrel[n][r*32+o] = sum_i h[n][i] * rel_w[r][i][o]
// ---------------------------------------------------------------------------
__global__ __launch_bounds__(256) void k_hrel(const float* __restrict__ h,
        const float* __restrict__ rel_w, float* __restrict__ hrel, int N) {
    __shared__ float hbuf[32 * 33];
    int t = threadIdx.x;
    int n0 = blockIdx.x * 32;
    #pragma unroll
    for (int k = 0; k < 4; ++k) {
        int idx = t + 256 * k;
        int row = idx >> 5, col = idx & 31;
        int n = n0 + row;
        hbuf[row * 33 + col] = (n < N) ? h[n * 32 + col] : 0.f;
    }
    __syncthreads();
    int w = t >> 6;
    int lane = t & 63;
    const float4* Wg = (const float4*)rel_w;
    int base_f4 = (lane >> 3) * 256 + (lane & 7);
    float4 a0[8], a1[8];
    #pragma unroll
    for (int j = 0; j < 8; ++j) {
        a0[j] = make_float4(0.f, 0.f, 0.f, 0.f);
        a1[j] = make_float4(0.f, 0.f, 0.f, 0.f);
    }
    int brow = w * 8;
    #pragma unroll 4
    for (int i = 0; i < 32; ++i) {
        float4 w0 = Wg[base_f4 + i * 8];
        float4 w1 = Wg[base_f4 + i * 8 + 2048];
        #pragma unroll
        for (int j = 0; j < 8; ++j) {
            float hv = hbuf[(brow + j) * 33 + i];
            a0[j].x += hv * w0.x; a0[j].y += hv * w0.y; a0[j].z += hv * w0.z; a0[j].w += hv * w0.w;
            a1[j].x += hv * w1.x; a1[j].y += hv * w1.y; a1[j].z += hv * w1.z; a1[j].w += hv * w1.w;
        }
    }
    #pragma unroll
    for (int j = 0; j < 8; ++j) {
        int n = n0 + brow + j;
        if (n < N) {
            *(float4*)&hrel[(size_t)n * 512 + lane * 4]       = a0[j];
            *(float4*)&hrel[(size_t)n * 512 + 256 + lane * 4] = a1[j];
        }
    }
}

// ---------------------------------------------------------------------------
// k_node_agg: one node per 64-lane wave, 2 edges per step (one per 32-half).
// CSR gather, attention via DPP row-reduce, register accumulate, fused output.
// No atomics, no __syncthreads.
// ---------------------------------------------------------------------------
__global__ __launch_bounds__(256) void k_node_agg(
        const float* __restrict__ hrel, const float* __restrict__ hA1,
        const float* __restrict__ hA2, const float* __restrict__ relA,
        const float* __restrict__ B_w, const float* __restrict__ B_b,
        const float* __restrict__ curr, const float* __restrict__ bias,
        const int* __restrict__ rowptr, const int* __restrict__ packed,
        const float* __restrict__ scale_s,
        float* __restrict__ out, int N) {
    int t = threadIdx.x;
    int wave = t >> 6, t64 = t & 63;
    int half = t64 >> 5, o = t64 & 31;
    int n = blockIdx.x * 4 + wave;
    if (n >= N) return;
    int r0 = rowptr[n], r1 = rowptr[n + 1];
    float hA2n = hA2[n * 32 + o];
    float bwo = B_w[o];
    float bb  = B_b[0];
    float acc = 0.f;
    for (int c0 = r0; c0 < r1; c0 += 64) {
        int j = c0 + t64;
        int pk = (j < r1) ? packed[j] : 0;
        int m = r1 - c0; if (m > 64) m = 64;
        for (int k = 0; k < m; k += 2) {
            int idx = k + half;                    // edge c0+idx for this half
            int pke = __shfl(pk, idx, 64);
            int s = pke & 0xFFFFF;
            int r = pke >> 20;
            float msg = hrel[(size_t)s * 512 + (r << 5) + o];
            float z = hA1[(s << 5) + o] + hA2n + relA[(r << 5) + o];
            float p = fmaxf(z, 0.f) * bwo;
            // 32-lane sum on VALU pipe: row_shr 1/2/4/8 + row_bcast15
            p = dpp_add_f<0x111>(p);
            p = dpp_add_f<0x112>(p);
            p = dpp_add_f<0x114>(p);
            p = dpp_add_f<0x118>(p);
            p = dpp_add_f<0x142>(p);               // lane31/63 hold half-sums
            p = __shfl(p, 31, 32) + bb;            // broadcast within each half
            float a = 1.f / (1.f + __expf(-p));
            acc += (idx < m) ? a * msg : 0.f;
        }
    }
    acc += __shfl_xor(acc, 32, 64);                // combine the two halves
    if (half == 0) {
        float deg = (float)(r1 - r0);
        float smean = scale_s[0] / (float)N;
        float scale = logf(deg + 1.0f);
        float v = curr[n * 32 + o] + (scale / smean) * acc / fmaxf(deg, 1.f) + bias[o];
        out[n * 32 + o] = fmaxf(v, 0.f);
    }
}

extern "C" void kernel_launch(void* const* d_in, const int* in_sizes, int n_in,
                              void* d_out, int out_size, void* d_ws, size_t ws_size,
                              hipStream_t stream) {
    const float* h        = (const float*)d_in[0];
    const float* weight   = (const float*)d_in[1];
    const float* w_comp   = (const float*)d_in[2];
    const float* slw      = (const float*)d_in[3];
    const float* bias     = (const float*)d_in[4];
    const float* attn_emb = (const float*)d_in[5];
    const float* A_w      = (const float*)d_in[6];
    const float* A_b      = (const float*)d_in[7];
    const float* B_w      = (const float*)d_in[8];
    const float* B_b      = (const float*)d_in[9];
    const int*   src      = (const int*)d_in[10];
    const int*   dst      = (const int*)d_in[11];
    const int*   et       = (const int*)d_in[12];
    float*       out      = (float*)d_out;

    int N = in_sizes[0] / INP;
    int E = in_sizes[10];
    int nblk = (N + 255) / 256;

    char* ws = (char*)d_ws;
    size_t off = 0;
    auto alloc = [&](size_t nbytes) {
        char* p = ws + off;
        off += (nbytes + 63) & ~((size_t)63);
        return p;
    };
    int*   deg     = (int*)  alloc((size_t)N * 4);
    int*   cursor  = (int*)  alloc((size_t)N * 4);
    float* scale_s = (float*)alloc(4);
    size_t zero_bytes = off;                       // deg + cursor + scale_s
    int*   rowptr  = (int*)  alloc((size_t)(N + 1) * 4);
    int*   bsum    = (int*)  alloc((size_t)nblk * 4);
    float* rel_w   = (float*)alloc((size_t)NREL * 1024 * 4);
    float* relA    = (float*)alloc((size_t)NREL * 32 * 4);
    float* hA1     = (float*)alloc((size_t)N * 32 * 4);
    float* hA2     = (float*)alloc((size_t)N * 32 * 4);
    float* curr    = (float*)alloc((size_t)N * 32 * 4);
    int*   packed  = (int*)  alloc((size_t)E * 4);
    float* hrel    = (float*)alloc((size_t)N * 512 * 4);
    size_t need = off;

    if (ws_size < need) {
        fprintf(stderr, "kernel_launch: ws too small (%zu < %zu bytes) — no work launched\n",
                ws_size, need);
        return;
    }

    (void)hipMemsetAsync(d_ws, 0, zero_bytes, stream);

    k_prep<<<64, 256, 0, stream>>>(weight, w_comp, attn_emb, A_w, A_b, rel_w, relA);
    k_hist<<<(E + 255) / 256, 256, 0, stream>>>(dst, deg, E);
    k_scan1<<<nblk, 256, 0, stream>>>(deg, rowptr, bsum, scale_s, N);
    k_scan2<<<1, 1024, 0, stream>>>(bsum, rowptr, nblk, N);
    k_scan3<<<nblk, 256, 0, stream>>>(rowptr, bsum, N);
    k_scatter<<<(E + 255) / 256, 256, 0, stream>>>(src, dst, et, rowptr, cursor, packed, E);
    k_node_pre<<<(N + 7) / 8, 256, 0, stream>>>(h, A_w, slw, hA1, hA2, curr, N);
    k_hrel<<<(N + 31) / 32, 256, 0, stream>>>(h, rel_w, hrel, N);
    k_node_agg<<<(N + 3) / 4, 256, 0, stream>>>(hrel, hA1, hA2, relA, B_w, B_b,
                                                curr, bias, rowptr, packed,
                                                scale_s, out, N);
}

// Round 4
// 346.040 us; speedup vs baseline: 1.2677x; 1.1551x over previous
//
#include <hip/hip_runtime.h>
#include <hip/hip_fp16.h>
#include <cstdio>
#include <cstdint>

#define NREL 16
#define NBASE 8

// ---------------------------------------------------------------------------
// DPP-based partial-row add (VALU pipe, not LDS): x += dpp_shifted(x).
// ---------------------------------------------------------------------------
template <int CTRL>
__device__ __forceinline__ float dpp_add_f(float x) {
    int xi = __builtin_bit_cast(int, x);
    int yi = __builtin_amdgcn_update_dpp(0, xi, CTRL, 0xF, 0xF, true);
    return x + __builtin_bit_cast(float, yi);
}

// ---------------------------------------------------------------------------
// k_fused1: three independent jobs, selected by block range:
//   [0, nb_pre)            node_pre: hA1(fp16) = h@A_w[0:32], hA2 = h@A_w[32:64],
//                                    curr = h@slw          (8 nodes/block)
//   [nb_pre, +nb_hist)     hist:     deg[dst[e]] += 1
//   [nb_pre+nb_hist, +64)  prep:     rel_w = w_comp@weight; relA = attn_emb@A_w3+A_b
// ---------------------------------------------------------------------------
__global__ __launch_bounds__(256) void k_fused1(
        const float* __restrict__ h, const float* __restrict__ A_w,
        const float* __restrict__ slw,
        const float* __restrict__ weight, const float* __restrict__ w_comp,
        const float* __restrict__ attn_emb, const float* __restrict__ A_b,
        const int* __restrict__ dst,
        __half* __restrict__ hA1, float* __restrict__ hA2, float* __restrict__ curr,
        float* __restrict__ rel_w, float* __restrict__ relA, int* __restrict__ deg,
        int N, int E, int nb_pre, int nb_hist) {
    __shared__ __align__(16) float Wall[32 * 128];   // [i][c]: c<32 A1, <64 A2, <96 slw
    __shared__ float hbuf[8 * 33];
    int bx = blockIdx.x;
    int t = threadIdx.x;
    if (bx < nb_pre) {
        // ---- node_pre ----
        #pragma unroll
        for (int k = 0; k < 16; ++k) {
            int idx = t + 256 * k;
            int i = idx >> 7, c = idx & 127;
            float v = 0.f;
            if (c < 32)       v = A_w[i * 32 + c];
            else if (c < 64)  v = A_w[(32 + i) * 32 + (c - 32)];
            else if (c < 96)  v = slw[i * 32 + (c - 64)];
            Wall[idx] = v;
        }
        int n0 = bx * 8;
        {
            int row = t >> 5, col = t & 31;
            int n = n0 + row;
            hbuf[row * 33 + col] = (n < N) ? h[n * 32 + col] : 0.f;
        }
        __syncthreads();
        int nl = t >> 5;
        int c4 = (t & 31) * 4;
        float4 acc = {0.f, 0.f, 0.f, 0.f};
        #pragma unroll 8
        for (int i = 0; i < 32; ++i) {
            float hv = hbuf[nl * 33 + i];
            float4 w = *(const float4*)&Wall[i * 128 + c4];
            acc.x += hv * w.x; acc.y += hv * w.y; acc.z += hv * w.z; acc.w += hv * w.w;
        }
        int n = n0 + nl;
        if (n < N) {
            if (c4 < 32) {
                *(__half2*)&hA1[n * 32 + c4]     = __floats2half2_rn(acc.x, acc.y);
                *(__half2*)&hA1[n * 32 + c4 + 2] = __floats2half2_rn(acc.z, acc.w);
            } else if (c4 < 64) {
                *(float4*)&hA2[n * 32 + (c4 - 32)] = acc;
            } else if (c4 < 96) {
                *(float4*)&curr[n * 32 + (c4 - 64)] = acc;
            }
        }
    } else if (bx < nb_pre + nb_hist) {
        // ---- hist ----
        int e = (bx - nb_pre) * 256 + t;
        if (e < E) atomicAdd(&deg[dst[e]], 1);
    } else {
        // ---- prep ----
        int idx = (bx - nb_pre - nb_hist) * 256 + t;     // 0..16383
        int r = idx >> 10, io = idx & 1023;
        float acc = 0.f;
        #pragma unroll
        for (int b = 0; b < NBASE; ++b)
            acc += w_comp[r * NBASE + b] * weight[b * 1024 + io];
        rel_w[idx] = acc;
        if (idx < NREL * 32) {
            int rr = idx >> 5, o = idx & 31;
            float a = A_b[o];
            #pragma unroll 8
            for (int i = 0; i < 32; ++i)
                a += attn_emb[rr * 32 + i] * A_w[(64 + i) * 32 + o];
            relA[idx] = a;
        }
    }
}

// ---------------------------------------------------------------------------
// k_scan1: per-block exclusive scan of deg -> rowptr_p (block-local) + bsum
// (raw block totals). Also sum of log(deg+1) into scale_s.
// ---------------------------------------------------------------------------
__global__ __launch_bounds__(256) void k_scan1(const int* __restrict__ deg,
        int* __restrict__ rowptr_p, int* __restrict__ bsum,
        float* __restrict__ scale_s, int N) {
    __shared__ int sd[256];
    __shared__ float sf[256];
    int t = threadIdx.x;
    int gid = blockIdx.x * 256 + t;
    int v = (gid < N) ? deg[gid] : 0;
    sd[t] = v;
    sf[t] = (gid < N) ? logf((float)v + 1.0f) : 0.f;
    __syncthreads();
    for (int off = 1; off < 256; off <<= 1) {
        int x = (t >= off) ? sd[t - off] : 0;
        __syncthreads();
        sd[t] += x;
        __syncthreads();
    }
    if (gid < N) rowptr_p[gid] = sd[t] - v;
    if (t == 255) bsum[blockIdx.x] = sd[255];
    for (int s2 = 128; s2 > 0; s2 >>= 1) {
        if (t < s2) sf[t] += sf[t + s2];
        __syncthreads();
    }
    if (t == 0) atomicAdd(scale_s, sf[0]);
}

// ---------------------------------------------------------------------------
// k_scan2: single block exclusive-scans bsum in place (chunked for any nblk).
// ---------------------------------------------------------------------------
__global__ __launch_bounds__(1024) void k_scan2(int* __restrict__ bsum, int nblk) {
    __shared__ int sd[1024];
    __shared__ int carry;
    int t = threadIdx.x;
    if (t == 0) carry = 0;
    __syncthreads();
    for (int base = 0; base < nblk; base += 1024) {
        int v = (base + t < nblk) ? bsum[base + t] : 0;
        sd[t] = v;
        __syncthreads();
        for (int off = 1; off < 1024; off <<= 1) {
            int x = (t >= off) ? sd[t - off] : 0;
            __syncthreads();
            sd[t] += x;
            __syncthreads();
        }
        int c = carry;
        if (base + t < nblk) bsum[base + t] = sd[t] - v + c;
        int tot = sd[1023];
        __syncthreads();
        if (t == 0) carry = c + tot;
        __syncthreads();
    }
}

// ---------------------------------------------------------------------------
// k_fused2: two independent jobs by block range:
//   [0, nb_hrel)         hrel16[n][r*32+o] = fp16( sum_i h[n][i]*rel_w[r][i][o] )
//   [nb_hrel, +nb_scat)  scatter: packed[rowptr(d) + cursor(d)++] = src|et<<20
// rowptr(d) reconstructed as rowptr_p[d] + bsum[d>>8].
// ---------------------------------------------------------------------------
__global__ __launch_bounds__(256) void k_fused2(
        const float* __restrict__ h, const float* __restrict__ rel_w,
        __half* __restrict__ hrel16,
        const int* __restrict__ src, const int* __restrict__ dst,
        const int* __restrict__ et,
        const int* __restrict__ rowptr_p, const int* __restrict__ bsum,
        int* __restrict__ cursor, int* __restrict__ packed,
        int N, int E, int nb_hrel) {
    __shared__ float hbuf[32 * 33];
    int bx = blockIdx.x;
    int t = threadIdx.x;
    if (bx < nb_hrel) {
        // ---- hrel (fp16 out) ----
        int n0 = bx * 32;
        #pragma unroll
        for (int k = 0; k < 4; ++k) {
            int idx = t + 256 * k;
            int row = idx >> 5, col = idx & 31;
            int n = n0 + row;
            hbuf[row * 33 + col] = (n < N) ? h[n * 32 + col] : 0.f;
        }
        __syncthreads();
        int w = t >> 6;
        int lane = t & 63;
        const float4* Wg = (const float4*)rel_w;
        int base_f4 = (lane >> 3) * 256 + (lane & 7);
        float4 a0[8], a1[8];
        #pragma unroll
        for (int j = 0; j < 8; ++j) {
            a0[j] = make_float4(0.f, 0.f, 0.f, 0.f);
            a1[j] = make_float4(0.f, 0.f, 0.f, 0.f);
        }
        int brow = w * 8;
        #pragma unroll 4
        for (int i = 0; i < 32; ++i) {
            float4 w0 = Wg[base_f4 + i * 8];
            float4 w1 = Wg[base_f4 + i * 8 + 2048];
            #pragma unroll
            for (int j = 0; j < 8; ++j) {
                float hv = hbuf[(brow + j) * 33 + i];
                a0[j].x += hv * w0.x; a0[j].y += hv * w0.y; a0[j].z += hv * w0.z; a0[j].w += hv * w0.w;
                a1[j].x += hv * w1.x; a1[j].y += hv * w1.y; a1[j].z += hv * w1.z; a1[j].w += hv * w1.w;
            }
        }
        #pragma unroll
        for (int j = 0; j < 8; ++j) {
            int n = n0 + brow + j;
            if (n < N) {
                size_t b0 = (size_t)n * 512 + lane * 4;
                *(__half2*)&hrel16[b0]           = __floats2half2_rn(a0[j].x, a0[j].y);
                *(__half2*)&hrel16[b0 + 2]       = __floats2half2_rn(a0[j].z, a0[j].w);
                *(__half2*)&hrel16[b0 + 256]     = __floats2half2_rn(a1[j].x, a1[j].y);
                *(__half2*)&hrel16[b0 + 258]     = __floats2half2_rn(a1[j].z, a1[j].w);
            }
        }
    } else {
        // ---- scatter ----
        int e = (bx - nb_hrel) * 256 + t;
        if (e < E) {
            int d = dst[e];
            int pos = rowptr_p[d] + bsum[d >> 8] + atomicAdd(&cursor[d], 1);
            packed[pos] = src[e] | (et[e] << 20);
        }
    }
}

// ---------------------------------------------------------------------------
// k_node_agg: one node per 64-lane wave, 2 edges per step (one per 32-half).
// CSR gather from fp16 tables, DPP attention reduce, register accumulate,
// fused epilogue. No atomics, no __syncthreads.
// ---------------------------------------------------------------------------
__global__ __launch_bounds__(256) void k_node_agg(
        const __half* __restrict__ hrel16, const __half* __restrict__ hA1,
        const float* __restrict__ hA2, const float* __restrict__ relA,
        const float* __restrict__ B_w, const float* __restrict__ B_b,
        const float* __restrict__ curr, const float* __restrict__ bias,
        const int* __restrict__ rowptr_p, const int* __restrict__ bsum,
        const int* __restrict__ packed, const float* __restrict__ scale_s,
        float* __restrict__ out, int N, int E) {
    int t = threadIdx.x;
    int wave = t >> 6, t64 = t & 63;
    int half = t64 >> 5, o = t64 & 31;
    int n = blockIdx.x * 4 + wave;
    if (n >= N) return;
    int r0 = rowptr_p[n] + bsum[n >> 8];
    int r1 = (n + 1 < N) ? (rowptr_p[n + 1] + bsum[(n + 1) >> 8]) : E;
    float hA2n = hA2[n * 32 + o];
    float bwo = B_w[o];
    float bb  = B_b[0];
    float acc = 0.f;
    for (int c0 = r0; c0 < r1; c0 += 64) {
        int j = c0 + t64;
        int pk = (j < r1) ? packed[j] : 0;
        int m = r1 - c0; if (m > 64) m = 64;
        for (int k = 0; k < m; k += 2) {
            int idx = k + half;                    // edge c0+idx for this half
            int pke = __shfl(pk, idx, 64);
            int s = pke & 0xFFFFF;
            int r = pke >> 20;
            float msg = __half2float(hrel16[(size_t)s * 512 + (r << 5) + o]);
            float z = __half2float(hA1[(s << 5) + o]) + hA2n + relA[(r << 5) + o];
            float p = fmaxf(z, 0.f) * bwo;
            // 32-lane sum on VALU pipe: row_shr 1/2/4/8 + row_bcast15
            p = dpp_add_f<0x111>(p);
            p = dpp_add_f<0x112>(p);
            p = dpp_add_f<0x114>(p);
            p = dpp_add_f<0x118>(p);
            p = dpp_add_f<0x142>(p);               // lane31/63 hold half-sums
            p = __shfl(p, 31, 32) + bb;            // broadcast within each half
            float a = 1.f / (1.f + __expf(-p));
            acc += (idx < m) ? a * msg : 0.f;
        }
    }
    acc += __shfl_xor(acc, 32, 64);                // combine the two halves
    if (half == 0) {
        float deg = (float)(r1 - r0);
        float smean = scale_s[0] / (float)N;
        float scale = logf(deg + 1.0f);
        float v = curr[n * 32 + o] + (scale / smean) * acc / fmaxf(deg, 1.f) + bias[o];
        out[n * 32 + o] = fmaxf(v, 0.f);
    }
}

extern "C" void kernel_launch(void* const* d_in, const int* in_sizes, int n_in,
                              void* d_out, int out_size, void* d_ws, size_t ws_size,
                              hipStream_t stream) {
    const float* h        = (const float*)d_in[0];
    const float* weight   = (const float*)d_in[1];
    const float* w_comp   = (const float*)d_in[2];
    const float* slw      = (const float*)d_in[3];
    const float* bias     = (const float*)d_in[4];
    const float* attn_emb = (const float*)d_in[5];
    const float* A_w      = (const float*)d_in[6];
    const float* A_b      = (const float*)d_in[7];
    const float* B_w      = (const float*)d_in[8];
    const float* B_b      = (const float*)d_in[9];
    const int*   src      = (const int*)d_in[10];
    const int*   dst      = (const int*)d_in[11];
    const int*   et       = (const int*)d_in[12];
    float*       out      = (float*)d_out;

    int N = in_sizes[0] / 32;
    int E = in_sizes[10];
    int nblk = (N + 255) / 256;

    char* ws = (char*)d_ws;
    size_t off = 0;
    auto alloc = [&](size_t nbytes) {
        char* p = ws + off;
        off += (nbytes + 63) & ~((size_t)63);
        return p;
    };
    int*    deg     = (int*)   alloc((size_t)N * 4);
    int*    cursor  = (int*)   alloc((size_t)N * 4);
    float*  scale_s = (float*) alloc(4);
    size_t zero_bytes = off;                       // deg + cursor + scale_s
    int*    rowptr_p= (int*)   alloc((size_t)N * 4);
    int*    bsum    = (int*)   alloc((size_t)nblk * 4);
    float*  rel_w   = (float*) alloc((size_t)NREL * 1024 * 4);
    float*  relA    = (float*) alloc((size_t)NREL * 32 * 4);
    __half* hA1     = (__half*)alloc((size_t)N * 32 * 2);
    float*  hA2     = (float*) alloc((size_t)N * 32 * 4);
    float*  curr    = (float*) alloc((size_t)N * 32 * 4);
    int*    packed  = (int*)   alloc((size_t)E * 4);
    __half* hrel16  = (__half*)alloc((size_t)N * 512 * 2);
    size_t need = off;

    if (ws_size < need) {
        fprintf(stderr, "kernel_launch: ws too small (%zu < %zu bytes) — no work launched\n",
                ws_size, need);
        return;
    }

    (void)hipMemsetAsync(d_ws, 0, zero_bytes, stream);

    int nb_pre  = (N + 7) / 8;
    int nb_hist = (E + 255) / 256;
    int nb_prep = 64;
    k_fused1<<<nb_pre + nb_hist + nb_prep, 256, 0, stream>>>(
        h, A_w, slw, weight, w_comp, attn_emb, A_b, dst,
        hA1, hA2, curr, rel_w, relA, deg, N, E, nb_pre, nb_hist);

    k_scan1<<<nblk, 256, 0, stream>>>(deg, rowptr_p, bsum, scale_s, N);
    k_scan2<<<1, 1024, 0, stream>>>(bsum, nblk);

    int nb_hrel = (N + 31) / 32;
    int nb_scat = (E + 255) / 256;
    k_fused2<<<nb_hrel + nb_scat, 256, 0, stream>>>(
        h, rel_w, hrel16, src, dst, et, rowptr_p, bsum, cursor, packed,
        N, E, nb_hrel);

    k_node_agg<<<(N + 3) / 4, 256, 0, stream>>>(
        hrel16, hA1, hA2, relA, B_w, B_b, curr, bias,
        rowptr_p, bsum, packed, scale_s, out, N, E);
}